// Round 1
// baseline (458.884 us; speedup 1.0000x reference)
//
#include <hip/hip_runtime.h>
#include <cstddef>

#define G_   2048
#define NPG_ 512
#define CPG_ 128
#define CPG2_ 32
#define N0_  (G_*NPG_)
#define M1_  (G_*CPG_)
#define M2_  (G_*CPG2_)

// output layout (floats): z_what[G,64] | z_mask[G,64] | mu[G,128] | sigma[G,128] | f[G,256]
#define OFF_ZW 0
#define OFF_ZM (G_*64)
#define OFF_MU (2*G_*64)
#define OFF_SG (2*G_*64 + G_*128)
#define OFF_F  (2*G_*64 + 2*G_*128)

__device__ __forceinline__ float celu_f(float x)     { return x > 0.f ? x : expm1f(x); }
__device__ __forceinline__ float softplus_f(float x) { return fmaxf(x, 0.f) + log1pf(expf(-fabsf(x))); }

// ---------------- conv1: [N0 edges] -> f1 [M1,32], one block per glimpse ----------------
__global__ __launch_bounds__(256) void k_conv1(
    const float* __restrict__ rgb, const float* __restrict__ pos, const float* __restrict__ pos1,
    const int* __restrict__ idx0, const float* __restrict__ W1l, const float* __restrict__ b1l,
    const float* __restrict__ W1g, const float* __restrict__ b1g, float* __restrict__ f1)
{
    const int g = blockIdx.x, t = threadIdx.x;
    __shared__ float agg[CPG_*20];   // stride 20: float4-aligned (80B), j in [0,16)
    __shared__ float cnt[CPG_];
    __shared__ float sW1l[64], sb1l[16], sW1g[512];

    for (int i = t; i < CPG_*20; i += 256) agg[i] = 0.f;
    if (t < CPG_) cnt[t] = 0.f;
    if (t < 64)  sW1l[t] = W1l[t];
    if (t < 16)  sb1l[t] = b1l[t];
    for (int i = t; i < 512; i += 256) sW1g[i] = W1g[i];
    __syncthreads();

    #pragma unroll
    for (int r = 0; r < 2; r++) {
        const int p  = g*NPG_ + r*256 + t;
        const float x0 = rgb[p];
        const int c  = idx0[p];
        const int lc = c - g*CPG_;
        const float rx = pos[p*3+0] - pos1[c*3+0];
        const float ry = pos[p*3+1] - pos1[c*3+1];
        const float rz = pos[p*3+2] - pos1[c*3+2];
        #pragma unroll
        for (int j = 0; j < 16; j++) {
            float h = sb1l[j] + x0*sW1l[j] + rx*sW1l[16+j] + ry*sW1l[32+j] + rz*sW1l[48+j];
            atomicAdd(&agg[lc*20 + j], celu_f(h));
        }
        atomicAdd(&cnt[lc], 1.f);
    }
    __syncthreads();

    for (int i = t; i < CPG_*16; i += 256) {
        const int lc = i >> 4, j = i & 15;
        agg[lc*20 + j] = agg[lc*20 + j] / fmaxf(cnt[lc], 1.f);
    }
    __syncthreads();

    // global conv: [128,16] @ [16,32] -> celu -> f1
    const int oc = t & 31;
    float wreg[16];
    #pragma unroll
    for (int j = 0; j < 16; j++) wreg[j] = sW1g[j*32 + oc];
    const float bg = b1g[oc];
    #pragma unroll
    for (int i = 0; i < 16; i++) {
        const int lc = (t >> 5) + i*8;
        float a = bg;
        #pragma unroll
        for (int j = 0; j < 16; j += 4) {
            const float4 a4 = *(const float4*)&agg[lc*20 + j];
            a += a4.x*wreg[j] + a4.y*wreg[j+1] + a4.z*wreg[j+2] + a4.w*wreg[j+3];
        }
        f1[(size_t)(g*CPG_ + lc)*32 + oc] = celu_f(a);
    }
}

// ---------------- conv2: [M1 edges] -> f2 [M2,128], one block per glimpse ----------------
__global__ __launch_bounds__(256) void k_conv2(
    const float* __restrict__ f1, const float* __restrict__ pos1, const float* __restrict__ pos2,
    const int* __restrict__ idx1, const float* __restrict__ W2l, const float* __restrict__ b2l,
    const float* __restrict__ W2g, const float* __restrict__ b2g, float* __restrict__ f2)
{
    const int g = blockIdx.x, t = threadIdx.x;
    __shared__ float sW2l[35*64];
    __shared__ float sb2l[64];
    __shared__ float xs[CPG_*36];    // 35 inputs padded to 36 (144B rows, 16B aligned)
    __shared__ int   slc[CPG_];
    __shared__ float agg[CPG2_*64];
    __shared__ float cnt[CPG2_];
    __shared__ float sW2g[64*128];

    for (int i = t; i < 2240; i += 256) sW2l[i] = W2l[i];
    if (t < 64) sb2l[t] = b2l[t];
    for (int i = t; i < CPG2_*64; i += 256) agg[i] = 0.f;
    if (t < CPG2_) cnt[t] = 0.f;
    for (int i = t; i < 8192; i += 256) sW2g[i] = W2g[i];
    for (int i = t; i < CPG_*32; i += 256) {
        const int le = i >> 5, j = i & 31;
        xs[le*36 + j] = f1[(size_t)g*CPG_*32 + i];
    }
    if (t < CPG_) {
        const int c2 = idx1[g*CPG_ + t];
        slc[t] = c2 - g*CPG2_;
        #pragma unroll
        for (int d = 0; d < 3; d++)
            xs[t*36 + 32 + d] = pos1[(g*CPG_ + t)*3 + d] - pos2[c2*3 + d];
    }
    __syncthreads();

    // local conv: 128 edges x 64 ch, thread: ch=t&63, edges le = q+4i
    const int ch = t & 63, q = t >> 6;
    float acc[32];
    #pragma unroll
    for (int i = 0; i < 32; i++) acc[i] = sb2l[ch];
    for (int k = 0; k < 32; k += 4) {
        const float w0 = sW2l[(k+0)*64+ch], w1 = sW2l[(k+1)*64+ch];
        const float w2 = sW2l[(k+2)*64+ch], w3 = sW2l[(k+3)*64+ch];
        #pragma unroll
        for (int i = 0; i < 32; i++) {
            const float4 x4 = *(const float4*)&xs[(q + 4*i)*36 + k];
            acc[i] += x4.x*w0 + x4.y*w1 + x4.z*w2 + x4.w*w3;
        }
    }
    for (int k = 32; k < 35; k++) {
        const float w = sW2l[k*64 + ch];
        #pragma unroll
        for (int i = 0; i < 32; i++) acc[i] += xs[(q + 4*i)*36 + k] * w;
    }
    #pragma unroll
    for (int i = 0; i < 32; i++) {
        const int le = q + 4*i;
        atomicAdd(&agg[slc[le]*64 + ch], celu_f(acc[i]));
    }
    if (t < CPG_) atomicAdd(&cnt[slc[t]], 1.f);
    __syncthreads();

    for (int i = t; i < CPG2_*64; i += 256)
        agg[i] = agg[i] / fmaxf(cnt[i >> 6], 1.f);
    __syncthreads();

    // global conv: [32,64] @ [64,128] -> celu -> f2
    const int oc = t & 127, hf = t >> 7;
    float acc2[16];
    #pragma unroll
    for (int i = 0; i < 16; i++) acc2[i] = b2g[oc];
    for (int k = 0; k < 64; k += 4) {
        const float w0 = sW2g[(k+0)*128+oc], w1 = sW2g[(k+1)*128+oc];
        const float w2 = sW2g[(k+2)*128+oc], w3 = sW2g[(k+3)*128+oc];
        #pragma unroll
        for (int i = 0; i < 16; i++) {
            const float4 a4 = *(const float4*)&agg[(hf + 2*i)*64 + k];
            acc2[i] += a4.x*w0 + a4.y*w1 + a4.z*w2 + a4.w*w3;
        }
    }
    #pragma unroll
    for (int i = 0; i < 16; i++) {
        const int ls = hf + 2*i;
        f2[(size_t)(g*CPG2_ + ls)*128 + oc] = celu_f(acc2[i]);
    }
}

// ---------------- conv3 + linear + sample: 2 glimpses per block ----------------
__global__ __launch_bounds__(256) void k_conv3(
    const float* __restrict__ f2, const float* __restrict__ pos2,
    const float* __restrict__ W3l, const float* __restrict__ b3l,
    const float* __restrict__ W3g, const float* __restrict__ b3g,
    const float* __restrict__ Wlin, const float* __restrict__ blin,
    const float* __restrict__ eps, float* __restrict__ out)
{
    const int g0 = blockIdx.x * 2, t = threadIdx.x;
    __shared__ float xs[64*132];   // 2 glimpses x 32 rows x (128 feat + 3 pos, pad 132)
    __shared__ float red[512];
    __shared__ float agg[256];
    __shared__ float f3s[512];
    __shared__ float outs[512];

    for (int i = t; i < 64*128; i += 256)
        xs[(i >> 7)*132 + (i & 127)] = f2[(size_t)g0*CPG2_*128 + i];
    if (t < 192) {
        const int r = t / 3, d = t % 3;
        xs[r*132 + 128 + d] = pos2[(g0*CPG2_ + r)*3 + d];
    }
    __syncthreads();

    // local conv: per glimpse [32,131] @ [131,128], celu, mean over 32 rows
    const int ch = t & 127, hf = t >> 7;
    float acc[2][16];
    {
        const float b = b3l[ch];
        #pragma unroll
        for (int gl = 0; gl < 2; gl++)
            #pragma unroll
            for (int i = 0; i < 16; i++) acc[gl][i] = b;
    }
    for (int k = 0; k < 128; k += 4) {
        const float w0 = W3l[(k+0)*128+ch], w1 = W3l[(k+1)*128+ch];
        const float w2 = W3l[(k+2)*128+ch], w3 = W3l[(k+3)*128+ch];
        #pragma unroll
        for (int gl = 0; gl < 2; gl++)
        #pragma unroll
        for (int i = 0; i < 16; i++) {
            const float4 x4 = *(const float4*)&xs[(gl*32 + hf + 2*i)*132 + k];
            acc[gl][i] += x4.x*w0 + x4.y*w1 + x4.z*w2 + x4.w*w3;
        }
    }
    for (int k = 128; k < 131; k++) {
        const float w = W3l[k*128 + ch];
        #pragma unroll
        for (int gl = 0; gl < 2; gl++)
        #pragma unroll
        for (int i = 0; i < 16; i++)
            acc[gl][i] += xs[(gl*32 + hf + 2*i)*132 + k] * w;
    }
    #pragma unroll
    for (int gl = 0; gl < 2; gl++) {
        float ps = 0.f;
        #pragma unroll
        for (int i = 0; i < 16; i++) ps += celu_f(acc[gl][i]);
        red[gl*256 + t] = ps;
    }
    __syncthreads();
    if (t < 128) {
        agg[t]       = (red[t]       + red[128 + t]) * (1.f/32.f);
        agg[128 + t] = (red[256 + t] + red[384 + t]) * (1.f/32.f);
    }
    __syncthreads();

    // global conv: agg[128] @ W3g[128,256] + b3g -> celu -> f3 (both glimpses share W loads)
    {
        float a0 = b3g[t], a1 = a0;
        for (int k = 0; k < 128; k += 4) {
            const float4 ga = *(const float4*)&agg[k];
            const float4 gb = *(const float4*)&agg[128 + k];
            const float w0 = W3g[(k+0)*256+t], w1 = W3g[(k+1)*256+t];
            const float w2 = W3g[(k+2)*256+t], w3 = W3g[(k+3)*256+t];
            a0 += ga.x*w0 + ga.y*w1 + ga.z*w2 + ga.w*w3;
            a1 += gb.x*w0 + gb.y*w1 + gb.z*w2 + gb.w*w3;
        }
        f3s[t]       = celu_f(a0);
        f3s[256 + t] = celu_f(a1);
    }
    __syncthreads();

    // linear head: f3[256] @ Wlin[256,256] + blin
    {
        float a0 = blin[t], a1 = a0;
        for (int k = 0; k < 256; k += 4) {
            const float4 fa = *(const float4*)&f3s[k];
            const float4 fb = *(const float4*)&f3s[256 + k];
            const float w0 = Wlin[(k+0)*256+t], w1 = Wlin[(k+1)*256+t];
            const float w2 = Wlin[(k+2)*256+t], w3 = Wlin[(k+3)*256+t];
            a0 += fa.x*w0 + fa.y*w1 + fa.z*w2 + fa.w*w3;
            a1 += fb.x*w0 + fb.y*w1 + fb.z*w2 + fb.w*w3;
        }
        outs[t]       = a0;
        outs[256 + t] = a1;
    }
    out[OFF_F + (size_t)g0*256 + t]     = f3s[t];
    out[OFF_F + (size_t)(g0+1)*256 + t] = f3s[256 + t];
    __syncthreads();

    if (t < 128) {
        #pragma unroll
        for (int gl = 0; gl < 2; gl++) {
            const int g = g0 + gl;
            const float mu    = outs[gl*256 + t];
            const float sigma = softplus_f(outs[gl*256 + 128 + t]);
            const float z     = mu + sigma * eps[g*128 + t];
            out[OFF_MU + g*128 + t] = mu;
            out[OFF_SG + g*128 + t] = sigma;
            if (t < 64) out[OFF_ZW + g*64 + t] = z;
            else        out[OFF_ZM + g*64 + (t - 64)] = z;
        }
    }
}

extern "C" void kernel_launch(void* const* d_in, const int* in_sizes, int n_in,
                              void* d_out, int out_size, void* d_ws, size_t ws_size,
                              hipStream_t stream)
{
    const float* rgb  = (const float*)d_in[0];
    const float* pos  = (const float*)d_in[1];
    const float* pos1 = (const float*)d_in[2];
    const float* pos2 = (const float*)d_in[3];
    const int*   idx0 = (const int*)d_in[4];
    const int*   idx1 = (const int*)d_in[5];
    // d_in[6] (out_index2) is implicit: e // 32
    const float* eps  = (const float*)d_in[7];
    const float* W1l = (const float*)d_in[8],  *b1l = (const float*)d_in[9];
    const float* W1g = (const float*)d_in[10], *b1g = (const float*)d_in[11];
    const float* W2l = (const float*)d_in[12], *b2l = (const float*)d_in[13];
    const float* W2g = (const float*)d_in[14], *b2g = (const float*)d_in[15];
    const float* W3l = (const float*)d_in[16], *b3l = (const float*)d_in[17];
    const float* W3g = (const float*)d_in[18], *b3g = (const float*)d_in[19];
    const float* Wlin = (const float*)d_in[20], *blin = (const float*)d_in[21];

    float* f1 = (float*)d_ws;                 // M1*32 floats = 33.5 MB
    float* f2 = f1 + (size_t)M1_*32;          // M2*128 floats = 33.5 MB
    float* outp = (float*)d_out;

    k_conv1<<<G_,   256, 0, stream>>>(rgb, pos, pos1, idx0, W1l, b1l, W1g, b1g, f1);
    k_conv2<<<G_,   256, 0, stream>>>(f1, pos1, pos2, idx1, W2l, b2l, W2g, b2g, f2);
    k_conv3<<<G_/2, 256, 0, stream>>>(f2, pos2, W3l, b3l, W3g, b3g, Wlin, blin, eps, outp);
}